// Round 10
// baseline (1250.976 us; speedup 1.0000x reference)
//
#include <hip/hip_runtime.h>
#include <math.h>

#define T_STEPS 256
#define NB 4096

// ---------------- fast fp64 math (accuracy ~2e-16 rel, range |x| < 600) ----------------
// exp(x * s) where Cs = s * 64/ln2 was folded by the caller.
__device__ __forceinline__ double fexp_scaled(double x, double Cs, const double* __restrict__ T){
    const double MAGIC = 6755399441055744.0;             // 2^52 + 2^51
    double zz = fma(x, Cs, MAGIC);                        // n = round(x*Cs), in low bits
    int    ni = __double2loint(zz);
    double nd = zz - MAGIC;                               // n as double (exact)
    double f  = fma(x, Cs, -nd);                          // residual in [-0.5, 0.5], 1-rounding
    double t  = f * 1.0830424696249145e-2;                // * ln2/64
    double p  = 8.3333333333333332e-03;                   // 1/120
    p = fma(t, p, 4.1666666666666664e-02);                // 1/24
    p = fma(t, p, 1.6666666666666666e-01);                // 1/6
    p = fma(t, p, 5.0e-01);
    p = fma(t, p, 1.0);
    p = fma(t, p, 1.0);                                   // e^t
    double tb = T[ni & 63];                               // 2^(j/64)
    double s  = __longlong_as_double((long long)(1023 + (ni >> 6)) << 52);  // 2^m
    return tb * p * s;
}
__device__ __forceinline__ double frcp(double d){
    double r;
    asm("v_rcp_f64 %0, %1" : "=v"(r) : "v"(d));           // ~2^-14..2^-29 approx
    r = r * fma(-d, r, 2.0);                              // NR 1
    r = r * fma(-d, r, 2.0);                              // NR 2 -> ~0.5 ulp
    return r;
}
#define C_NEG  (-92.332482616893656843)   // -64/ln2  -> exp(-x)
#define C_2POS (184.66496523378731369)    // 128/ln2  -> exp(2x)

__global__ __launch_bounds__(256, 2)
void rssm_kernel(const float* __restrict__ X, const float* __restrict__ A,
                 const float* __restrict__ H0, const float* __restrict__ G,
                 const float* __restrict__ Wih, const float* __restrict__ bih,
                 const float* __restrict__ Whh, const float* __restrict__ bhh,
                 const float* __restrict__ Wenc, const float* __restrict__ benc,
                 const float* __restrict__ Wdec, const float* __restrict__ bdec,
                 float* __restrict__ out)   // d_out is FP32
{
    // Dynamic LDS, 75344 B total (2 blocks/CU at <=80KB).
    extern __shared__ char smem[];
    double (*sWhh)[33]   = (double(*)[33])(smem);            // [96][33] fp64  25344
    double (*sHd)[33]    = (double(*)[33])(smem + 25344);    // [8][33]  fp64   2112
    double *sExpT        = (double*)(smem + 27456);          // [64]     fp64    512
    float (*sWihz)[65]   = (float(*)[65])(smem + 27968);     // [96][65]       24960
    float (*sWiha)[17]   = (float(*)[17])(smem + 52928);     // [96][17]        6528
    float (*sWenchT)[64] = (float(*)[64])(smem + 59456);     // [32][64]        8192
    float (*sWenceT)[64] = (float(*)[64])(smem + 67648);     // [10][64]        2560
    float (*sWdech)[37]  = (float(*)[37])(smem + 70208);     // [10][37]        1480
    float (*sWdecz)[65]  = (float(*)[65])(smem + 71688);     // [10][65]        2600
    float (*sHf)[33]     = (float(*)[33])(smem + 74288);     // [8][33]         1056

    const int tid = threadIdx.x;
    const int i   = tid & 31;          // component lane within element
    const int e   = tid >> 5;          // element slot in block (0..7)
    const int n   = blockIdx.x * 8 + e;

    for (int idx = tid; idx < 96*64; idx += 256){ int r = idx >> 6, c = idx & 63; sWihz[r][c] = Wih[r*80 + c]; }
    for (int idx = tid; idx < 96*16; idx += 256){ int r = idx >> 4, k = idx & 15; sWiha[r][k] = Wih[r*80 + 64 + k]; }
    for (int idx = tid; idx < 96*32; idx += 256){ int r = idx >> 5, k = idx & 31; sWhh[r][k] = (double)Whh[r*32 + k]; }
    for (int idx = tid; idx < 32*64; idx += 256){ int k = idx >> 6, j = idx & 63; sWenchT[k][j] = Wenc[j*42 + k]; }
    for (int idx = tid; idx < 10*64; idx += 256){ int k = idx >> 6, j = idx & 63; sWenceT[k][j] = Wenc[j*42 + 32 + k]; }
    for (int idx = tid; idx < 10*32; idx += 256){ int o = idx >> 5, k = idx & 31; sWdech[o][k] = Wdec[o*96 + k]; }
    for (int idx = tid; idx < 10*64; idx += 256){ int o = idx >> 6, c = idx & 63; sWdecz[o][c] = Wdec[o*96 + 32 + c]; }
    for (int idx = tid; idx < 64;    idx += 256){ sExpT[idx] = exp2((double)idx * 0.015625); }
    __syncthreads();

    // biases (r,z gates merge b_ih+b_hh; n gate split: b_hh[n] sits inside r*h_n)
    const double br  = (double)bih[i]      + (double)bhh[i];
    const double bz  = (double)bih[32+i]   + (double)bhh[32+i];
    const double bni = (double)bih[64+i];
    const double bnh = (double)bhh[64+i];
    const double be0 = (double)benc[2*i], be1 = (double)benc[2*i+1];
    const float  bd  = (i < 10) ? bdec[i] : 0.0f;
    const int    drow = (i < 10) ? i : 9;  // dec weight row (lanes >=10 discard)

    // h state lives in LDS; each lane owns component i
    double hown = (double)H0[(size_t)n * 32 + i];
    sHd[e][i] = hown;                  // intra-wave visibility; no barrier needed
    sHf[e][i] = (float)hown;

    int zsel[8];                       // winning flat column (0..63) per z-group

    const size_t HOFF = (size_t)T_STEPS * NB * 10;   // x_logits elements
    const size_t ZOFF = HOFF + (size_t)T_STEPS * NB * 32;
    const int base = tid & 32;         // element's lane base within the wave

    // ---- software-prefetched step inputs (hide HBM latency under compute) ----
    float2 g2;  float ex[10];  float ar[16] = {};
    g2 = *reinterpret_cast<const float2*>(G + (size_t)n*64 + 2*i);   // G[t=0]
    {
        const float* xr = X + (size_t)n*10;                          // X[t=0]
        #pragma unroll
        for (int c = 0; c < 5; ++c){
            float2 v = *reinterpret_cast<const float2*>(xr + 2*c);
            ex[2*c] = v.x; ex[2*c+1] = v.y;
        }
    }

    #pragma unroll 1
    for (int t = 0; t < T_STEPS; ++t){
        const size_t tn = (size_t)t * NB + n;

        // ---- prefetch NEXT step's inputs first (used ~2000 cycles later) ----
        const int tp = (t + 1 < T_STEPS) ? t + 1 : t;   // clamp (wave-uniform)
        const size_t tpn = (size_t)tp * NB + n;
        float2 g2n = *reinterpret_cast<const float2*>(G + tpn*64 + 2*i);
        float exn[10];
        {
            const float* xr = X + tpn*10;
            #pragma unroll
            for (int c = 0; c < 5; ++c){
                float2 v = *reinterpret_cast<const float2*>(xr + 2*c);
                exn[2*c] = v.x; exn[2*c+1] = v.y;
            }
        }
        float arn[16];   // A[t], consumed by next iteration's GRU
        {
            const float4* arow = reinterpret_cast<const float4*>(A + tn*16);
            #pragma unroll
            for (int c = 0; c < 4; ++c){
                float4 v = arow[c];
                arn[4*c+0]=v.x; arn[4*c+1]=v.y; arn[4*c+2]=v.z; arn[4*c+3]=v.w;
            }
        }

        if (t > 0){
            // ---- GRU (fp64): h_t = gru([z_{t-1}, a_{t-1}], h_{t-1}) ----
            double gr = br, gz = bz, gn = bni, hn = bnh;
            #pragma unroll
            for (int g = 0; g < 8; ++g){   // one-hot z part: gather selected columns
                int col = zsel[g];
                gr += (double)sWihz[i][col];
                gz += (double)sWihz[32+i][col];
                gn += (double)sWihz[64+i][col];
            }
            #pragma unroll
            for (int k = 0; k < 16; ++k){  // dense a part (ar = A[t-1], prefetched)
                double ak = (double)ar[k];
                gr = fma((double)sWiha[i][k],    ak, gr);
                gz = fma((double)sWiha[32+i][k], ak, gz);
                gn = fma((double)sWiha[64+i][k], ak, gn);
            }
            #pragma unroll
            for (int k = 0; k < 32; ++k){  // hidden part: fp64 weights, NO conversions
                double hk = sHd[e][k];
                gr = fma(sWhh[i][k],    hk, gr);
                gz = fma(sWhh[32+i][k], hk, gz);
                hn = fma(sWhh[64+i][k], hk, hn);
            }
            double r   = frcp(1.0 + fexp_scaled(gr, C_NEG, sExpT));
            double zg  = frcp(1.0 + fexp_scaled(gz, C_NEG, sExpT));
            double arg = gn + r * hn;
            double e2  = fexp_scaled(arg, C_2POS, sExpT);     // exp(2*arg)
            double nn  = fma(-2.0, frcp(e2 + 1.0), 1.0);      // tanh(arg)
            hown = (1.0 - zg) * nn + zg * hown;

            // publish h_new (all reads of h_old are in program order above; same wave)
            sHd[e][i] = hown;
            sHf[e][i] = (float)hown;
        }

        // h_all output (fp32)
        const float hf = (float)hown;
        out[HOFF + tn*32 + i] = hf;

        // ---- ENC (fp64 logits): argmax(logits + gumbel) ----
        double l0 = be0, l1 = be1;
        #pragma unroll
        for (int k = 0; k < 32; ++k){
            double hk = sHd[e][k];
            float2 w = *reinterpret_cast<const float2*>(&sWenchT[k][2*i]);
            l0 = fma((double)w.x, hk, l0);
            l1 = fma((double)w.y, hk, l1);
        }
        #pragma unroll
        for (int k = 0; k < 10; ++k){
            float2 w = *reinterpret_cast<const float2*>(&sWenceT[k][2*i]);
            double ek = (double)ex[k];
            l0 = fma((double)w.x, ek, l0);
            l1 = fma((double)w.y, ek, l1);
        }
        double y0 = l0 + (double)g2.x, y1 = l1 + (double)g2.y;
        double m; int idxv;
        if (y1 > y0){ m = y1; idxv = 2*i + 1; } else { m = y0; idxv = 2*i; }
        #pragma unroll
        for (int d = 1; d <= 2; d <<= 1){   // butterfly argmax over the 4-lane cluster
            double mo = __shfl_xor(m, d, 64);
            int    io = __shfl_xor(idxv, d, 64);
            if (mo > m || (mo == m && io < idxv)){ m = mo; idxv = io; }
        }

        // z one-hot output (fp32)
        {
            float2 zv;
            zv.x = (idxv == 2*i    ) ? 1.0f : 0.0f;
            zv.y = (idxv == 2*i + 1) ? 1.0f : 0.0f;
            *reinterpret_cast<float2*>(out + ZOFF + tn*64 + 2*i) = zv;
        }

        // distribute the 8 group winners to every lane of the element
        #pragma unroll
        for (int g = 0; g < 8; ++g){
            zsel[g] = __shfl(idxv, base + 4*g, 64);
        }

        // ---- DEC in fp32 (x_logits needs only ~1e-3; error ~3e-6) ----
        float dacc = bd;
        #pragma unroll
        for (int k = 0; k < 32; ++k){
            dacc = fmaf(sWdech[drow][k], sHf[e][k], dacc);
        }
        if (i < 10){
            float acc = dacc;
            #pragma unroll
            for (int g = 0; g < 8; ++g) acc += sWdecz[i][zsel[g]];
            out[tn*10 + i] = acc;
        }

        // rotate prefetched inputs into place for the next iteration
        g2 = g2n;
        #pragma unroll
        for (int k = 0; k < 10; ++k) ex[k] = exn[k];
        #pragma unroll
        for (int k = 0; k < 16; ++k) ar[k] = arn[k];
    }
}

extern "C" void kernel_launch(void* const* d_in, const int* in_sizes, int n_in,
                              void* d_out, int out_size, void* d_ws, size_t ws_size,
                              hipStream_t stream)
{
    // Defensive input binding by unique element count (no-op if dict order holds).
    const float *x   = (const float*)d_in[0];
    const float *a   = (const float*)d_in[1];
    const float *h0  = (const float*)d_in[2];
    const float *g   = (const float*)d_in[3];
    const float *wih = (const float*)d_in[4];
    const float *bih = (const float*)d_in[5];
    const float *whh = (const float*)d_in[6];
    const float *bhh = (const float*)d_in[7];
    const float *wenc= (const float*)d_in[8];
    const float *benc= (const float*)d_in[9];
    const float *wdec= (const float*)d_in[10];
    const float *bdec= (const float*)d_in[11];

    if (n_in == 12) {
        const float *b96a = nullptr, *b96b = nullptr;
        const float *tx=nullptr,*ta=nullptr,*th0=nullptr,*tg=nullptr,*twih=nullptr,
                    *twhh=nullptr,*twenc=nullptr,*tbenc=nullptr,*twdec=nullptr,*tbdec=nullptr;
        for (int k = 0; k < 12; ++k) {
            const float* p = (const float*)d_in[k];
            switch (in_sizes[k]) {
                case 10485760: tx = p;    break;  // x
                case 16777216: ta = p;    break;  // a
                case 131072:   th0 = p;   break;  // h0
                case 67108864: tg = p;    break;  // gumbel
                case 7680:     twih = p;  break;  // W_ih
                case 3072:     twhh = p;  break;  // W_hh
                case 2688:     twenc = p; break;  // W_enc
                case 64:       tbenc = p; break;  // b_enc
                case 960:      twdec = p; break;  // W_dec
                case 10:       tbdec = p; break;  // b_dec
                case 96:       if (!b96a) b96a = p; else b96b = p; break; // b_ih / b_hh (both zero)
                default: break;
            }
        }
        if (tx && ta && th0 && tg && twih && twhh && twenc && tbenc && twdec && tbdec && b96a && b96b) {
            x = tx; a = ta; h0 = th0; g = tg;
            wih = twih; whh = twhh; wenc = twenc; benc = tbenc; wdec = twdec; bdec = tbdec;
            bih = b96a; bhh = b96b;
        }
    }

    const int SMEM_BYTES = 75344;
    hipFuncSetAttribute((const void*)rssm_kernel,
                        hipFuncAttributeMaxDynamicSharedMemorySize, SMEM_BYTES);
    rssm_kernel<<<512, 256, SMEM_BYTES, stream>>>(
        x, a, h0, g, wih, bih, whh, bhh, wenc, benc, wdec, bdec,
        (float*)d_out);
}